// Round 20
// baseline (68.370 us; speedup 1.0000x reference)
//
#include <hip/hip_runtime.h>
#include <hip/hip_bf16.h>
#include <math.h>

#define B_SZ 16384
#define D_SZ 512
#define C_SZ 2000

// scales: fm*ASCALE, w*WSCALE, h1*HSCALE all land in e4m3 normal range
#define ASCALE 64.f
#define WSCALE 16.f
#define HSCALE 1024.f
#define INV1 (1.f / (ASCALE * WSCALE))   // 1/1024
#define INV2 (1.f / (HSCALE * WSCALE))   // 1/16384

typedef float f32x4 __attribute__((ext_vector_type(4)));
typedef unsigned short ushort8 __attribute__((ext_vector_type(8)));

__device__ __forceinline__ f32x4 ntload4(const float* p) {
  return __builtin_nontemporal_load((const f32x4*)p);
}
// pack 4 f32 -> 4 fp8(e4m3) bytes
__device__ __forceinline__ unsigned int pk4_fp8(float a, float b, float c, float d) {
  int r = __builtin_amdgcn_cvt_pk_fp8_f32(a, b, 0, false);
  r = __builtin_amdgcn_cvt_pk_fp8_f32(c, d, r, true);
  return (unsigned int)r;
}
__device__ __forceinline__ unsigned char f2fp8(float v) {
  int r = __builtin_amdgcn_cvt_pk_fp8_f32(v, 0.f, 0, false);
  return (unsigned char)(r & 0xff);
}

// ---------------- K0: fused prep ---------------------------------------------
// blocks 0..127  : cs/css partial sums (atomicAdd into zeroed cs/css)
// blocks 128..255: w1,w2 -> fp8 line-packed layout [k>>5][n][k&31], *WSCALE
__global__ __launch_bounds__(256) void prep(
    const float* __restrict__ cw, const float* __restrict__ prior,
    const float* __restrict__ w1, const float* __restrict__ w2,
    float* __restrict__ cs, float* __restrict__ css,
    unsigned char* __restrict__ w1q, unsigned char* __restrict__ w2q) {
  __shared__ float ls[2][4][64];
  __shared__ float tile[64][65];
  const int t = threadIdx.x;
  int bid = blockIdx.x;
  if (bid < 128) {
    const int dl = t & 63, g = t >> 6;
    const int dchunk = bid & 7, cchunk = bid >> 3;  // 8 x 16
    const int d = (dchunk << 6) + dl;
    const int cstart = cchunk * 125, cend = cstart + 125;
    float s = 0.f, ss = 0.f;
    for (int c = cstart + g; c < cend; c += 4) {
      float w = cw[(size_t)c * D_SZ + d] * prior[c];
      s += w; ss += w * w;
    }
    ls[0][g][dl] = s; ls[1][g][dl] = ss;
    __syncthreads();
    if (t < 64) {
      atomicAdd(cs + (dchunk << 6) + t,
                ls[0][0][t] + ls[0][1][t] + ls[0][2][t] + ls[0][3][t]);
      atomicAdd(css + (dchunk << 6) + t,
                ls[1][0][t] + ls[1][1][t] + ls[1][2][t] + ls[1][3][t]);
    }
    return;
  }
  bid -= 128;
  const float* src = w1; unsigned char* dst = w1q;
  if (bid >= 64) { src = w2; dst = w2q; bid -= 64; }
  const int kt = (bid >> 3) << 6;
  const int nt = (bid & 7) << 6;
  const int r0 = t >> 4, c0 = (t & 15) << 2;
  #pragma unroll
  for (int rr = 0; rr < 4; ++rr) {
    const int r = r0 + rr * 16;
    float4 v = *(const float4*)(src + (size_t)(kt + r) * 512 + nt + c0);
    tile[r][c0] = v.x; tile[r][c0 + 1] = v.y;
    tile[r][c0 + 2] = v.z; tile[r][c0 + 3] = v.w;
  }
  __syncthreads();
  // thread t covers output row n = nt+nr, 16 consecutive k at kc
  const int nr = t >> 2, kc = (t & 3) << 4;
  const int n = nt + nr;
  uint4 o;
  o.x = pk4_fp8(tile[kc + 0][nr] * WSCALE, tile[kc + 1][nr] * WSCALE,
                tile[kc + 2][nr] * WSCALE, tile[kc + 3][nr] * WSCALE);
  o.y = pk4_fp8(tile[kc + 4][nr] * WSCALE, tile[kc + 5][nr] * WSCALE,
                tile[kc + 6][nr] * WSCALE, tile[kc + 7][nr] * WSCALE);
  o.z = pk4_fp8(tile[kc + 8][nr] * WSCALE, tile[kc + 9][nr] * WSCALE,
                tile[kc + 10][nr] * WSCALE, tile[kc + 11][nr] * WSCALE);
  o.w = pk4_fp8(tile[kc + 12][nr] * WSCALE, tile[kc + 13][nr] * WSCALE,
                tile[kc + 14][nr] * WSCALE, tile[kc + 15][nr] * WSCALE);
  // line-packed: [k>>5][n][k&31]; 16B store fits within one chunk
  *(uint4*)(dst + ((size_t)((kt + kc) >> 5) << 14) + (n << 5) + (kc & 31)) = o;
}

// ---------------- K1: mega — 512 blocks x 32 rows, 512 threads, 2 blocks/CU -
__device__ __forceinline__ float fme(float u, float i, float c, float s, float ssq,
                                     float& reg) {
  float ucm = fmaf(u, s, 0.5f * (s * s - ssq));
  float s2 = u + i + c + ucm;
  float q2 = u * u + i * i + c * c + ucm * ucm;
  reg += u * u + i * i + c * c;
  return 0.5f * (s2 * s2 - q2);
}

__global__ __launch_bounds__(512, 4) void mega(
    const int* __restrict__ user, const int* __restrict__ item,
    const int* __restrict__ cate, const float* __restrict__ rate,
    const float* __restrict__ uw, const float* __restrict__ iw,
    const float* __restrict__ cw, const float* __restrict__ cs,
    const float* __restrict__ css,
    const unsigned char* __restrict__ w1q, const unsigned char* __restrict__ w2q,
    const float* __restrict__ b1, const float* __restrict__ b2,
    const float* __restrict__ w3, const float* __restrict__ b3,
    float* __restrict__ accs, float* __restrict__ out) {
  __shared__ unsigned char sA[32 * 512];    // A-panel / h1, fp8, XOR-swizzled (16KB)
  __shared__ float plog[8][36];
  __shared__ float red[8];
  const int t = threadIdx.x;
  const int lane = t & 63, w = t >> 6;      // 8 waves
  const int r0 = blockIdx.x << 5;           // 32 rows/block

  // ---- Phase A: gather + FM -> sA (fp8, scaled by ASCALE), coalesced ----
  {
    const int row = t >> 4;          // 0..31 (16 threads per row)
    const int g8 = (t & 15) << 3;    // 0..120
    const int b = r0 + row;
    const float* up = uw + (size_t)user[b] * D_SZ;
    const float* ip = iw + (size_t)item[b] * D_SZ;
    const float* cp = cw + (size_t)cate[b] * D_SZ;
    float regp = 0.f;
    const int aswz = (row & 7) << 3;
    #pragma unroll
    for (int j = 0; j < 4; ++j) {
      const int col = (j << 7) + g8;
      f32x4 u0 = ntload4(up + col), u1 = ntload4(up + col + 4);
      f32x4 i0 = ntload4(ip + col), i1 = ntload4(ip + col + 4);
      float4 g0 = *(const float4*)(cp + col), g1 = *(const float4*)(cp + col + 4);
      float4 s0 = *(const float4*)(cs + col), s1 = *(const float4*)(cs + col + 4);
      float4 q0 = *(const float4*)(css + col), q1 = *(const float4*)(css + col + 4);
      float o0 = fme(u0[0], i0[0], g0.x, s0.x, q0.x, regp) * ASCALE;
      float o1 = fme(u0[1], i0[1], g0.y, s0.y, q0.y, regp) * ASCALE;
      float o2 = fme(u0[2], i0[2], g0.z, s0.z, q0.z, regp) * ASCALE;
      float o3 = fme(u0[3], i0[3], g0.w, s0.w, q0.w, regp) * ASCALE;
      float o4 = fme(u1[0], i1[0], g1.x, s1.x, q1.x, regp) * ASCALE;
      float o5 = fme(u1[1], i1[1], g1.y, s1.y, q1.y, regp) * ASCALE;
      float o6 = fme(u1[2], i1[2], g1.z, s1.z, q1.z, regp) * ASCALE;
      float o7 = fme(u1[3], i1[3], g1.w, s1.w, q1.w, regp) * ASCALE;
      uint2 pv;
      pv.x = pk4_fp8(o0, o1, o2, o3);
      pv.y = pk4_fp8(o4, o5, o6, o7);
      *(uint2*)(sA + (((row << 9) + col) ^ aswz)) = pv;
    }
    #pragma unroll
    for (int off = 32; off; off >>= 1) regp += __shfl_down(regp, off);
    if (lane == 0) red[w] = regp;
  }
  __syncthreads();

  const int l15 = lane & 15;
  const int lk = (lane >> 4) << 3;        // byte(k)-offset within 32-run
  const int swz = (l15 & 7) << 3;
  const int nw = w << 6;                  // wave's n-base (64 cols per wave)
  const int rbase = (lane >> 4) << 2;
  const int nb0 = ((nw + l15) << 5) + lk; // B offset for nf=0; +nf<<9 per nf

  f32x4 acc[2][4];
  #pragma unroll
  for (int i = 0; i < 2; ++i)
    #pragma unroll
    for (int j = 0; j < 4; ++j) acc[i][j] = (f32x4){0.f, 0.f, 0.f, 0.f};

  // ---- Phase B: gemm1 (A = sA fp8 32 rows, B = w1q line-packed) ----
  for (int s = 0; s < 16; ++s) {
    const int k0 = (s << 5) + lk;
    const size_t cbase = (size_t)s << 14;
    long af[2], bb[4];
    #pragma unroll
    for (int mf = 0; mf < 2; ++mf)
      af[mf] = __builtin_bit_cast(long,
          *(const uint2*)(sA + ((((mf << 4) + l15) << 9) + (k0 ^ swz))));
    #pragma unroll
    for (int nf = 0; nf < 4; ++nf)
      bb[nf] = __builtin_bit_cast(long,
          *(const uint2*)(w1q + cbase + nb0 + (nf << 9)));
    __builtin_amdgcn_s_setprio(1);
    #pragma unroll
    for (int mf = 0; mf < 2; ++mf)
      #pragma unroll
      for (int nf = 0; nf < 4; ++nf)
        acc[mf][nf] = __builtin_amdgcn_mfma_f32_16x16x32_fp8_fp8(
            af[mf], bb[nf], acc[mf][nf], 0, 0, 0);
    __builtin_amdgcn_s_setprio(0);
  }
  __syncthreads();

  // ---- h1 = relu(acc*INV1 + b1) -> sA (fp8, scaled by HSCALE) ----
  {
    #pragma unroll
    for (int nf = 0; nf < 4; ++nf) {
      const int col = nw + (nf << 4) + l15;
      const float b1c = b1[col];
      #pragma unroll
      for (int mf = 0; mf < 2; ++mf) {
        #pragma unroll
        for (int q = 0; q < 4; ++q) {
          const int rw = (mf << 4) + rbase + q;
          float v = fmaxf(fmaf(acc[mf][nf][q], INV1, b1c), 0.f) * HSCALE;
          sA[(rw << 9) + (col ^ ((rw & 7) << 3))] = f2fp8(v);
        }
      }
    }
  }
  #pragma unroll
  for (int i = 0; i < 2; ++i)
    #pragma unroll
    for (int j = 0; j < 4; ++j) acc[i][j] = (f32x4){0.f, 0.f, 0.f, 0.f};
  __syncthreads();

  // ---- Phase C: gemm2 (A = h1 in sA, B = w2q line-packed) ----
  for (int s = 0; s < 16; ++s) {
    const int k0 = (s << 5) + lk;
    const size_t cbase = (size_t)s << 14;
    long af[2], bb[4];
    #pragma unroll
    for (int mf = 0; mf < 2; ++mf)
      af[mf] = __builtin_bit_cast(long,
          *(const uint2*)(sA + ((((mf << 4) + l15) << 9) + (k0 ^ swz))));
    #pragma unroll
    for (int nf = 0; nf < 4; ++nf)
      bb[nf] = __builtin_bit_cast(long,
          *(const uint2*)(w2q + cbase + nb0 + (nf << 9)));
    __builtin_amdgcn_s_setprio(1);
    #pragma unroll
    for (int mf = 0; mf < 2; ++mf)
      #pragma unroll
      for (int nf = 0; nf < 4; ++nf)
        acc[mf][nf] = __builtin_amdgcn_mfma_f32_16x16x32_fp8_fp8(
            af[mf], bb[nf], acc[mf][nf], 0, 0, 0);
    __builtin_amdgcn_s_setprio(0);
  }

  // ---- epilogue: relu(acc*INV2 + b2) dot w3 -> per-wave logit partials ----
  {
    float b2c[4], wv[4];
    #pragma unroll
    for (int nf = 0; nf < 4; ++nf) {
      const int n = nw + (nf << 4) + l15;
      b2c[nf] = b2[n];
      wv[nf] = w3[n];
    }
    #pragma unroll
    for (int mf = 0; mf < 2; ++mf) {
      #pragma unroll
      for (int q = 0; q < 4; ++q) {
        float v = 0.f;
        #pragma unroll
        for (int nf = 0; nf < 4; ++nf)
          v += fmaxf(fmaf(acc[mf][nf][q], INV2, b2c[nf]), 0.f) * wv[nf];
        v += __shfl_xor(v, 1);
        v += __shfl_xor(v, 2);
        v += __shfl_xor(v, 4);
        v += __shfl_xor(v, 8);
        if (l15 == 0) plog[w][(mf << 4) + rbase + q] = v;
      }
    }
  }
  __syncthreads();
  if (t < 32) {
    float s = 0.f;
    #pragma unroll
    for (int ww = 0; ww < 8; ++ww) s += plog[ww][t];
    float logit = s + b3[0];
    float pred = 1.f + 4.f / (1.f + expf(-logit));
    float d = pred - rate[r0 + t];
    float v = d * d;
    #pragma unroll
    for (int off = 16; off; off >>= 1) v += __shfl_down(v, off);
    if (t == 0) atomicAdd(&accs[0], v);
  } else if (t == 32) {
    atomicAdd(&accs[1], red[0] + red[1] + red[2] + red[3] +
                        red[4] + red[5] + red[6] + red[7]);
  }
  // ---- fused finalize: last block combines ----
  __syncthreads();
  if (t == 0) {
    __threadfence();
    unsigned int prev = atomicAdd((unsigned int*)(accs + 2), 1u);
    if (prev == 511u) {
      __threadfence();
      float l = atomicAdd(&accs[0], 0.f);
      float r = atomicAdd(&accs[1], 0.f);
      out[0] = l * (1.f / (float)B_SZ) + r * (0.5e-4f / (float)B_SZ);
    }
  }
}

extern "C" void kernel_launch(void* const* d_in, const int* in_sizes, int n_in,
                              void* d_out, int out_size, void* d_ws, size_t ws_size,
                              hipStream_t stream) {
  const int* user = (const int*)d_in[0];
  const int* item = (const int*)d_in[1];
  const int* cate = (const int*)d_in[2];
  const float* rate = (const float*)d_in[3];
  const float* uw = (const float*)d_in[4];
  const float* iw = (const float*)d_in[5];
  const float* cw = (const float*)d_in[6];
  const float* prior = (const float*)d_in[7];
  const float* w1 = (const float*)d_in[8];
  const float* b1 = (const float*)d_in[9];
  const float* w2 = (const float*)d_in[10];
  const float* b2 = (const float*)d_in[11];
  const float* w3 = (const float*)d_in[12];
  const float* b3 = (const float*)d_in[13];
  float* out = (float*)d_out;

  unsigned char* w1q = (unsigned char*)d_ws;     // [16][512][32] fp8, offset 0
  unsigned char* w2q = w1q + 262144;             // offset 256 KB
  float* cs   = (float*)(w2q + 262144);          // offset 512 KB
  float* css  = cs + 512;
  float* accs = css + 512;                       // [4]: loss, reg, fin_cnt, pad

  hipMemsetAsync(cs, 0, (512 + 512 + 4) * sizeof(float), stream);
  prep<<<256, 256, 0, stream>>>(cw, prior, w1, w2, cs, css, w1q, w2q);
  mega<<<512, 512, 0, stream>>>(user, item, cate, rate, uw, iw, cw, cs, css,
                                w1q, w2q, b1, b2, w3, b3, accs, out);
}

// Round 21
// 59.757 us; speedup vs baseline: 1.1441x; 1.1441x over previous
//
#include <hip/hip_runtime.h>
#include <hip/hip_bf16.h>
#include <math.h>

#define B_SZ 16384
#define D_SZ 512
#define C_SZ 2000

// scales: fm*ASCALE, w*WSCALE, h1*HSCALE all land in e4m3 normal range
#define ASCALE 64.f
#define WSCALE 16.f
#define HSCALE 1024.f
#define INV1 (1.f / (ASCALE * WSCALE))   // 1/1024
#define INV2 (1.f / (HSCALE * WSCALE))   // 1/16384

typedef float f32x4 __attribute__((ext_vector_type(4)));
typedef unsigned short ushort8 __attribute__((ext_vector_type(8)));

__device__ __forceinline__ unsigned short f2bf(float f) {
  unsigned int u = __builtin_bit_cast(unsigned int, f);
  u += 0x7fffu + ((u >> 16) & 1u);
  return (unsigned short)(u >> 16);
}
__device__ __forceinline__ float bf2f(unsigned short h) {
  unsigned int u = ((unsigned int)h) << 16;
  return __builtin_bit_cast(float, u);
}
__device__ __forceinline__ f32x4 ntload4(const float* p) {
  return __builtin_nontemporal_load((const f32x4*)p);
}
// pack 4 f32 -> 4 fp8(e4m3) bytes
__device__ __forceinline__ unsigned int pk4_fp8(float a, float b, float c, float d) {
  int r = __builtin_amdgcn_cvt_pk_fp8_f32(a, b, 0, false);
  r = __builtin_amdgcn_cvt_pk_fp8_f32(c, d, r, true);
  return (unsigned int)r;
}
__device__ __forceinline__ unsigned char f2fp8(float v) {
  int r = __builtin_amdgcn_cvt_pk_fp8_f32(v, 0.f, 0, false);
  return (unsigned char)(r & 0xff);
}

// ---------------- K0: fused prep ---------------------------------------------
// blocks 0..127  : cs/css partial sums (atomicAdd into zeroed cs/css)
// blocks 128..255: w1,w2 -> fp8 line-packed layout [k>>5][n][k&31], *WSCALE
// blocks 256..383: cw -> bf16 table cwb (halve cate L2 footprint so the
//                  512KB fp8 weight panels stay L2-resident during mega)
__global__ __launch_bounds__(256) void prep(
    const float* __restrict__ cw, const float* __restrict__ prior,
    const float* __restrict__ w1, const float* __restrict__ w2,
    float* __restrict__ cs, float* __restrict__ css,
    unsigned char* __restrict__ w1q, unsigned char* __restrict__ w2q,
    unsigned short* __restrict__ cwb) {
  __shared__ float ls[2][4][64];
  __shared__ float tile[64][65];
  const int t = threadIdx.x;
  int bid = blockIdx.x;
  if (bid < 128) {
    const int dl = t & 63, g = t >> 6;
    const int dchunk = bid & 7, cchunk = bid >> 3;  // 8 x 16
    const int d = (dchunk << 6) + dl;
    const int cstart = cchunk * 125, cend = cstart + 125;
    float s = 0.f, ss = 0.f;
    for (int c = cstart + g; c < cend; c += 4) {
      float w = cw[(size_t)c * D_SZ + d] * prior[c];
      s += w; ss += w * w;
    }
    ls[0][g][dl] = s; ls[1][g][dl] = ss;
    __syncthreads();
    if (t < 64) {
      atomicAdd(cs + (dchunk << 6) + t,
                ls[0][0][t] + ls[0][1][t] + ls[0][2][t] + ls[0][3][t]);
      atomicAdd(css + (dchunk << 6) + t,
                ls[1][0][t] + ls[1][1][t] + ls[1][2][t] + ls[1][3][t]);
    }
    return;
  }
  if (bid >= 256) {
    // cw (f32, 2000*512) -> cwb (bf16)
    const int g = ((bid - 256) << 8) + t;        // 0..32767
    for (int idx = g; idx < (C_SZ * D_SZ / 8); idx += 32768) {
      const float* s8 = cw + (size_t)idx * 8;
      float4 a = *(const float4*)s8, b = *(const float4*)(s8 + 4);
      ushort8 o;
      o[0] = f2bf(a.x); o[1] = f2bf(a.y); o[2] = f2bf(a.z); o[3] = f2bf(a.w);
      o[4] = f2bf(b.x); o[5] = f2bf(b.y); o[6] = f2bf(b.z); o[7] = f2bf(b.w);
      *(ushort8*)(cwb + (size_t)idx * 8) = o;
    }
    return;
  }
  bid -= 128;
  const float* src = w1; unsigned char* dst = w1q;
  if (bid >= 64) { src = w2; dst = w2q; bid -= 64; }
  const int kt = (bid >> 3) << 6;
  const int nt = (bid & 7) << 6;
  const int r0 = t >> 4, c0 = (t & 15) << 2;
  #pragma unroll
  for (int rr = 0; rr < 4; ++rr) {
    const int r = r0 + rr * 16;
    float4 v = *(const float4*)(src + (size_t)(kt + r) * 512 + nt + c0);
    tile[r][c0] = v.x; tile[r][c0 + 1] = v.y;
    tile[r][c0 + 2] = v.z; tile[r][c0 + 3] = v.w;
  }
  __syncthreads();
  // thread t covers output row n = nt+nr, 16 consecutive k at kc
  const int nr = t >> 2, kc = (t & 3) << 4;
  const int n = nt + nr;
  uint4 o;
  o.x = pk4_fp8(tile[kc + 0][nr] * WSCALE, tile[kc + 1][nr] * WSCALE,
                tile[kc + 2][nr] * WSCALE, tile[kc + 3][nr] * WSCALE);
  o.y = pk4_fp8(tile[kc + 4][nr] * WSCALE, tile[kc + 5][nr] * WSCALE,
                tile[kc + 6][nr] * WSCALE, tile[kc + 7][nr] * WSCALE);
  o.z = pk4_fp8(tile[kc + 8][nr] * WSCALE, tile[kc + 9][nr] * WSCALE,
                tile[kc + 10][nr] * WSCALE, tile[kc + 11][nr] * WSCALE);
  o.w = pk4_fp8(tile[kc + 12][nr] * WSCALE, tile[kc + 13][nr] * WSCALE,
                tile[kc + 14][nr] * WSCALE, tile[kc + 15][nr] * WSCALE);
  // line-packed: [k>>5][n][k&31]; 16B store fits within one chunk
  *(uint4*)(dst + ((size_t)((kt + kc) >> 5) << 14) + (n << 5) + (kc & 31)) = o;
}

// ---------------- K1: mega — 256 blocks x 64 rows, 512 threads, fp8 GEMMs ---
// K-split pipeline: gather cols 0-255 -> issue HBM loads for cols 256-511 ->
// gemm1 K-steps 0-7 (hides load latency) -> finish gather -> gemm1 K 8-15.
__device__ __forceinline__ float fme(float u, float i, float c, float s, float ssq,
                                     float& reg) {
  float ucm = fmaf(u, s, 0.5f * (s * s - ssq));
  float s2 = u + i + c + ucm;
  float q2 = u * u + i * i + c * c + ucm * ucm;
  reg += u * u + i * i + c * c;
  return 0.5f * (s2 * s2 - q2);
}

__global__ __launch_bounds__(512) void mega(
    const int* __restrict__ user, const int* __restrict__ item,
    const int* __restrict__ cate, const float* __restrict__ rate,
    const float* __restrict__ uw, const float* __restrict__ iw,
    const unsigned short* __restrict__ cwb, const float* __restrict__ cs,
    const float* __restrict__ css,
    const unsigned char* __restrict__ w1q, const unsigned char* __restrict__ w2q,
    const float* __restrict__ b1, const float* __restrict__ b2,
    const float* __restrict__ w3, const float* __restrict__ b3,
    float* __restrict__ accs, float* __restrict__ out) {
  __shared__ unsigned char sA[64 * 512];    // A-panel / h1, fp8, XOR-swizzled (32KB)
  __shared__ float plog[8][68];
  __shared__ float red[8];
  const int t = threadIdx.x;
  const int lane = t & 63, w = t >> 6;      // 8 waves
  const int r0 = blockIdx.x << 6;           // 64 rows/block

  const int row = t >> 3;          // 0..63
  const int g8 = (t & 7) << 3;     // 0..56
  const int aswz = (row & 7) << 3;
  const float* up = uw + (size_t)user[r0 + row] * D_SZ;
  const float* ip = iw + (size_t)item[r0 + row] * D_SZ;
  const unsigned short* cp = cwb + (size_t)cate[r0 + row] * D_SZ;
  float regp = 0.f;

  // ---- Phase A1: gather + FM for cols 0..255 -> sA ----
  #pragma unroll
  for (int j = 0; j < 4; ++j) {
    const int col = (j << 6) + g8;
    f32x4 u0 = ntload4(up + col), u1 = ntload4(up + col + 4);
    f32x4 i0 = ntload4(ip + col), i1 = ntload4(ip + col + 4);
    ushort8 cv = *(const ushort8*)(cp + col);
    float4 s0 = *(const float4*)(cs + col), s1 = *(const float4*)(cs + col + 4);
    float4 q0 = *(const float4*)(css + col), q1 = *(const float4*)(css + col + 4);
    float o0 = fme(u0[0], i0[0], bf2f(cv[0]), s0.x, q0.x, regp) * ASCALE;
    float o1 = fme(u0[1], i0[1], bf2f(cv[1]), s0.y, q0.y, regp) * ASCALE;
    float o2 = fme(u0[2], i0[2], bf2f(cv[2]), s0.z, q0.z, regp) * ASCALE;
    float o3 = fme(u0[3], i0[3], bf2f(cv[3]), s0.w, q0.w, regp) * ASCALE;
    float o4 = fme(u1[0], i1[0], bf2f(cv[4]), s1.x, q1.x, regp) * ASCALE;
    float o5 = fme(u1[1], i1[1], bf2f(cv[5]), s1.y, q1.y, regp) * ASCALE;
    float o6 = fme(u1[2], i1[2], bf2f(cv[6]), s1.z, q1.z, regp) * ASCALE;
    float o7 = fme(u1[3], i1[3], bf2f(cv[7]), s1.w, q1.w, regp) * ASCALE;
    uint2 pv;
    pv.x = pk4_fp8(o0, o1, o2, o3);
    pv.y = pk4_fp8(o4, o5, o6, o7);
    *(uint2*)(sA + (((row << 9) + col) ^ aswz)) = pv;
  }

  // ---- issue HBM loads for cols 256..511 now; latency hides under gemm1-h1
  f32x4 u2[4][2], i2[4][2];
  #pragma unroll
  for (int j = 0; j < 4; ++j) {
    const int col = ((j + 4) << 6) + g8;
    u2[j][0] = ntload4(up + col); u2[j][1] = ntload4(up + col + 4);
    i2[j][0] = ntload4(ip + col); i2[j][1] = ntload4(ip + col + 4);
  }
  __syncthreads();

  const int l15 = lane & 15;
  const int lk = (lane >> 4) << 3;        // byte(k)-offset within 32-run
  const int swz = (l15 & 7) << 3;
  const int nw = w << 6;                  // wave's n-base (64 cols per wave)
  const int rbase = (lane >> 4) << 2;
  const int nb0 = ((nw + l15) << 5) + lk; // B offset for nf=0; +nf<<9 per nf

  f32x4 acc[4][4];
  #pragma unroll
  for (int i = 0; i < 4; ++i)
    #pragma unroll
    for (int j = 0; j < 4; ++j) acc[i][j] = (f32x4){0.f, 0.f, 0.f, 0.f};

  // ---- gemm1 half 1: K-steps 0..7 (reads sA cols 0..255 only) ----
  #pragma unroll
  for (int s = 0; s < 8; ++s) {
    const int k0 = (s << 5) + lk;
    const size_t cbase = (size_t)s << 14;
    long af[4], bb[4];
    #pragma unroll
    for (int mf = 0; mf < 4; ++mf)
      af[mf] = __builtin_bit_cast(long,
          *(const uint2*)(sA + ((((mf << 4) + l15) << 9) + (k0 ^ swz))));
    #pragma unroll
    for (int nf = 0; nf < 4; ++nf)
      bb[nf] = __builtin_bit_cast(long,
          *(const uint2*)(w1q + cbase + nb0 + (nf << 9)));
    #pragma unroll
    for (int mf = 0; mf < 4; ++mf)
      #pragma unroll
      for (int nf = 0; nf < 4; ++nf)
        acc[mf][nf] = __builtin_amdgcn_mfma_f32_16x16x32_fp8_fp8(
            af[mf], bb[nf], acc[mf][nf], 0, 0, 0);
  }

  // ---- Phase A2: finish FM for cols 256..511 (u/i already in regs) ----
  #pragma unroll
  for (int j = 0; j < 4; ++j) {
    const int col = ((j + 4) << 6) + g8;
    ushort8 cv = *(const ushort8*)(cp + col);
    float4 s0 = *(const float4*)(cs + col), s1 = *(const float4*)(cs + col + 4);
    float4 q0 = *(const float4*)(css + col), q1 = *(const float4*)(css + col + 4);
    float o0 = fme(u2[j][0][0], i2[j][0][0], bf2f(cv[0]), s0.x, q0.x, regp) * ASCALE;
    float o1 = fme(u2[j][0][1], i2[j][0][1], bf2f(cv[1]), s0.y, q0.y, regp) * ASCALE;
    float o2 = fme(u2[j][0][2], i2[j][0][2], bf2f(cv[2]), s0.z, q0.z, regp) * ASCALE;
    float o3 = fme(u2[j][0][3], i2[j][0][3], bf2f(cv[3]), s0.w, q0.w, regp) * ASCALE;
    float o4 = fme(u2[j][1][0], i2[j][1][0], bf2f(cv[4]), s1.x, q1.x, regp) * ASCALE;
    float o5 = fme(u2[j][1][1], i2[j][1][1], bf2f(cv[5]), s1.y, q1.y, regp) * ASCALE;
    float o6 = fme(u2[j][1][2], i2[j][1][2], bf2f(cv[6]), s1.z, q1.z, regp) * ASCALE;
    float o7 = fme(u2[j][1][3], i2[j][1][3], bf2f(cv[7]), s1.w, q1.w, regp) * ASCALE;
    uint2 pv;
    pv.x = pk4_fp8(o0, o1, o2, o3);
    pv.y = pk4_fp8(o4, o5, o6, o7);
    *(uint2*)(sA + (((row << 9) + col) ^ aswz)) = pv;
  }
  #pragma unroll
  for (int off = 32; off; off >>= 1) regp += __shfl_down(regp, off);
  if (lane == 0) red[w] = regp;
  __syncthreads();

  // ---- gemm1 half 2: K-steps 8..15 ----
  #pragma unroll
  for (int s = 8; s < 16; ++s) {
    const int k0 = (s << 5) + lk;
    const size_t cbase = (size_t)s << 14;
    long af[4], bb[4];
    #pragma unroll
    for (int mf = 0; mf < 4; ++mf)
      af[mf] = __builtin_bit_cast(long,
          *(const uint2*)(sA + ((((mf << 4) + l15) << 9) + (k0 ^ swz))));
    #pragma unroll
    for (int nf = 0; nf < 4; ++nf)
      bb[nf] = __builtin_bit_cast(long,
          *(const uint2*)(w1q + cbase + nb0 + (nf << 9)));
    #pragma unroll
    for (int mf = 0; mf < 4; ++mf)
      #pragma unroll
      for (int nf = 0; nf < 4; ++nf)
        acc[mf][nf] = __builtin_amdgcn_mfma_f32_16x16x32_fp8_fp8(
            af[mf], bb[nf], acc[mf][nf], 0, 0, 0);
  }
  __syncthreads();

  // ---- h1 = relu(acc*INV1 + b1) -> sA (fp8, scaled by HSCALE) ----
  {
    #pragma unroll
    for (int nf = 0; nf < 4; ++nf) {
      const int col = nw + (nf << 4) + l15;
      const float b1c = b1[col];
      #pragma unroll
      for (int mf = 0; mf < 4; ++mf) {
        #pragma unroll
        for (int q = 0; q < 4; ++q) {
          const int rw = (mf << 4) + rbase + q;
          float v = fmaxf(fmaf(acc[mf][nf][q], INV1, b1c), 0.f) * HSCALE;
          sA[(rw << 9) + (col ^ ((rw & 7) << 3))] = f2fp8(v);
        }
      }
    }
  }
  #pragma unroll
  for (int i = 0; i < 4; ++i)
    #pragma unroll
    for (int j = 0; j < 4; ++j) acc[i][j] = (f32x4){0.f, 0.f, 0.f, 0.f};
  __syncthreads();

  // ---- Phase C: gemm2 (A = h1 in sA, B = w2q line-packed) ----
  for (int kt = 0; kt < 512; kt += 64) {
    #pragma unroll
    for (int ks = 0; ks < 2; ++ks) {
      const int k0 = kt + (ks << 5) + lk;
      const size_t cbase = (size_t)((kt >> 5) + ks) << 14;
      long af[4], bb[4];
      #pragma unroll
      for (int mf = 0; mf < 4; ++mf)
        af[mf] = __builtin_bit_cast(long,
            *(const uint2*)(sA + ((((mf << 4) + l15) << 9) + (k0 ^ swz))));
      #pragma unroll
      for (int nf = 0; nf < 4; ++nf)
        bb[nf] = __builtin_bit_cast(long,
            *(const uint2*)(w2q + cbase + nb0 + (nf << 9)));
      #pragma unroll
      for (int mf = 0; mf < 4; ++mf)
        #pragma unroll
        for (int nf = 0; nf < 4; ++nf)
          acc[mf][nf] = __builtin_amdgcn_mfma_f32_16x16x32_fp8_fp8(
              af[mf], bb[nf], acc[mf][nf], 0, 0, 0);
    }
  }

  // ---- epilogue: relu(acc*INV2 + b2) dot w3 -> per-wave logit partials ----
  {
    float b2c[4], wv[4];
    #pragma unroll
    for (int nf = 0; nf < 4; ++nf) {
      const int n = nw + (nf << 4) + l15;
      b2c[nf] = b2[n];
      wv[nf] = w3[n];
    }
    #pragma unroll
    for (int mf = 0; mf < 4; ++mf) {
      #pragma unroll
      for (int q = 0; q < 4; ++q) {
        float v = 0.f;
        #pragma unroll
        for (int nf = 0; nf < 4; ++nf)
          v += fmaxf(fmaf(acc[mf][nf][q], INV2, b2c[nf]), 0.f) * wv[nf];
        v += __shfl_xor(v, 1);
        v += __shfl_xor(v, 2);
        v += __shfl_xor(v, 4);
        v += __shfl_xor(v, 8);
        if (l15 == 0) plog[w][(mf << 4) + rbase + q] = v;
      }
    }
  }
  __syncthreads();
  if (t < 64) {
    float s = 0.f;
    #pragma unroll
    for (int ww = 0; ww < 8; ++ww) s += plog[ww][t];
    float logit = s + b3[0];
    float pred = 1.f + 4.f / (1.f + expf(-logit));
    float d = pred - rate[r0 + t];
    float v = d * d;
    #pragma unroll
    for (int off = 32; off; off >>= 1) v += __shfl_down(v, off);
    if (t == 0) atomicAdd(&accs[0], v);
  } else if (t == 64) {
    atomicAdd(&accs[1], red[0] + red[1] + red[2] + red[3] +
                        red[4] + red[5] + red[6] + red[7]);
  }
  // ---- fused finalize: last block combines ----
  __syncthreads();
  if (t == 0) {
    __threadfence();
    unsigned int prev = atomicAdd((unsigned int*)(accs + 2), 1u);
    if (prev == 255u) {
      __threadfence();
      float l = atomicAdd(&accs[0], 0.f);
      float r = atomicAdd(&accs[1], 0.f);
      out[0] = l * (1.f / (float)B_SZ) + r * (0.5e-4f / (float)B_SZ);
    }
  }
}

extern "C" void kernel_launch(void* const* d_in, const int* in_sizes, int n_in,
                              void* d_out, int out_size, void* d_ws, size_t ws_size,
                              hipStream_t stream) {
  const int* user = (const int*)d_in[0];
  const int* item = (const int*)d_in[1];
  const int* cate = (const int*)d_in[2];
  const float* rate = (const float*)d_in[3];
  const float* uw = (const float*)d_in[4];
  const float* iw = (const float*)d_in[5];
  const float* cw = (const float*)d_in[6];
  const float* prior = (const float*)d_in[7];
  const float* w1 = (const float*)d_in[8];
  const float* b1 = (const float*)d_in[9];
  const float* w2 = (const float*)d_in[10];
  const float* b2 = (const float*)d_in[11];
  const float* w3 = (const float*)d_in[12];
  const float* b3 = (const float*)d_in[13];
  float* out = (float*)d_out;

  unsigned char* w1q = (unsigned char*)d_ws;     // [16][512][32] fp8, offset 0
  unsigned char* w2q = w1q + 262144;             // offset 256 KB
  float* cs   = (float*)(w2q + 262144);          // offset 512 KB
  float* css  = cs + 512;
  float* accs = css + 512;                       // [4]: loss, reg, fin_cnt, pad
  unsigned short* cwb = (unsigned short*)(accs + 4);  // [2000*512] bf16, 16B-aligned

  hipMemsetAsync(cs, 0, (512 + 512 + 4) * sizeof(float), stream);
  prep<<<384, 256, 0, stream>>>(cw, prior, w1, w2, cs, css, w1q, w2q, cwb);
  mega<<<256, 512, 0, stream>>>(user, item, cate, rate, uw, iw, cwb, cs, css,
                                w1q, w2q, b1, b2, w3, b3, accs, out);
}